// Round 2
// baseline (935.369 us; speedup 1.0000x reference)
//
#include <hip/hip_runtime.h>
#include <hip/hip_bf16.h>

#define N_ATOMS 100000
#define M_NBRS 12
#define ATOM_F 64
#define NBR_F 41
#define OUT_DIM 128   // 2*ATOM_F
#define IN_DIM 169    // 2*ATOM_F + NBR_F

typedef __attribute__((ext_vector_type(8))) short short8;
typedef __attribute__((ext_vector_type(4))) float f32x4;

__device__ __forceinline__ unsigned short f2bf(float f) {
    union { float f; unsigned u; } v; v.f = f;
    unsigned u = v.u;
    return (unsigned short)((u + 0x7fffu + ((u >> 16) & 1u)) >> 16);
}
__device__ __forceinline__ float bf2f(unsigned short h) {
    union { unsigned u; float f; } v; v.u = ((unsigned)h) << 16;
    return v.f;
}
__device__ __forceinline__ unsigned pack_bf2(float lo, float hi) {
    return (unsigned)f2bf(lo) | (((unsigned)f2bf(hi)) << 16);
}
__device__ __forceinline__ float softplus_f(float x) {
    return fmaxf(x, 0.f) + __logf(1.f + __expf(-fabsf(x)));
}
__device__ __forceinline__ float sigmoid_f(float x) {
    return 1.f / (1.f + __expf(-x));
}

// ---------------------------------------------------------------------------
// P: per-atom precompute. abf[i] = bf16(atom_fea[i]);  A1b[i][o] = bf16(
//    W_self[o]·a_i + b[o]).  MFMA 16x16x32, rows = 16 atoms, cols = 128.
// No __syncthreads: each wave uses a private LDS region (wave-synchronous).
// ---------------------------------------------------------------------------
__global__ __launch_bounds__(256, 4) void k_prep(
    const float* __restrict__ atom, const float* __restrict__ W,
    const float* __restrict__ bias, unsigned* __restrict__ abf_u32,
    unsigned short* __restrict__ A1b)
{
    __shared__ unsigned Ap[4 * 16 * 36];   // per-wave 16 rows x 36 dw (64 bf16 + pad)
    const int tid = threadIdx.x;
    const int w = tid >> 6, l = tid & 63;
    const int r = l & 15, g = l >> 4;

    // B fragments (W_self^T): lane holds B[k = g*8+kk*32+j][col = nt*16+r]
    short8 bf[8][2];
    #pragma unroll
    for (int nt = 0; nt < 8; ++nt)
      #pragma unroll
      for (int kk = 0; kk < 2; ++kk)
        #pragma unroll
        for (int j = 0; j < 8; ++j) {
            int col = nt * 16 + r;
            int k = g * 8 + kk * 32 + j;
            bf[nt][kk][j] = (short)f2bf(W[col * IN_DIM + k]);
        }

    const int totalw = gridDim.x * 4;
    const int gw = blockIdx.x * 4 + w;
    const int step = totalw * 16;
    const int T = (N_ATOMS + step - 1) / step;
    unsigned* Aw = &Ap[w * 16 * 36];

    for (int t = 0; t < T; ++t) {
        int base = gw * 16 + t * step;
        #pragma unroll
        for (int sub = 0; sub < 4; ++sub) {
            int chunk = g * 4 + sub;          // 16 float4 chunks per row
            int a = base + r;
            float4 v = make_float4(0.f, 0.f, 0.f, 0.f);
            if (a < N_ATOMS)
                v = reinterpret_cast<const float4*>(atom)[a * 16 + chunk];
            unsigned d0 = pack_bf2(v.x, v.y);
            unsigned d1 = pack_bf2(v.z, v.w);
            Aw[r * 36 + chunk * 2]     = d0;
            Aw[r * 36 + chunk * 2 + 1] = d1;
            if (a < N_ATOMS) {
                abf_u32[a * 32 + chunk * 2]     = d0;
                abf_u32[a * 32 + chunk * 2 + 1] = d1;
            }
        }
        short8 af[2];
        #pragma unroll
        for (int kk = 0; kk < 2; ++kk) {
            union { uint4 u; short8 s; } u;
            u.u = *reinterpret_cast<const uint4*>(&Aw[r * 36 + kk * 16 + g * 4]);
            af[kk] = u.s;
        }
        #pragma unroll
        for (int nt = 0; nt < 8; ++nt) {
            f32x4 acc = {0.f, 0.f, 0.f, 0.f};
            acc = __builtin_amdgcn_mfma_f32_16x16x32_bf16(af[0], bf[nt][0], acc, 0, 0, 0);
            acc = __builtin_amdgcn_mfma_f32_16x16x32_bf16(af[1], bf[nt][1], acc, 0, 0, 0);
            int col = nt * 16 + r;
            float bb = bias[col];
            #pragma unroll
            for (int r4 = 0; r4 < 4; ++r4) {
                int a = base + g * 4 + r4;    // C row = quad*4 + reg
                if (a < N_ATOMS)
                    A1b[a * OUT_DIM + col] = f2bf(acc[r4] + bb);
            }
        }
    }
}

// ---------------------------------------------------------------------------
// M: one wave per atom per iteration, software-pipelined:
//   - idx row loaded 2 iterations ahead
//   - neighbor gathers / edge floats / A1 row / atom row loaded 1 iteration
//     ahead into registers (latency overlaps previous atom's MFMA+epilogue)
// No __syncthreads anywhere: per-wave LDS region.
// ---------------------------------------------------------------------------
struct Buf {
    unsigned ga[3], gb[3];          // gathered nbr bf16 (2 u32 per row)
    float e0[3], e1[3], e2[3], e3[3]; // raw edge floats
    unsigned a1v;                    // A1 row, 1 u32 (2 bf16) per lane
    float av;                        // atom row, 1 f32 per lane
};

__device__ __forceinline__ Buf issue_loads(
    int i, bool act, unsigned idxv,
    const unsigned* __restrict__ abf_u32, const float* __restrict__ nbr,
    const unsigned* __restrict__ A1u, const float* __restrict__ atom,
    int c, int g, int l)
{
    Buf b;
    if (act) {
        #pragma unroll
        for (int rr = 0; rr < 3; ++rr) {
            int r = rr * 4 + g;
            int j = (int)__shfl(idxv, r, 64);
            b.ga[rr] = abf_u32[j * 32 + c];
            b.gb[rr] = abf_u32[j * 32 + 16 + c];
            int eb = (i * M_NBRS + r) * NBR_F;
            b.e0[rr] = nbr[eb + 2 * c];
            b.e1[rr] = nbr[eb + 2 * c + 1];          // 2c+1 <= 31 < 41, safe
            b.e2[rr] = (c < 5) ? nbr[eb + 32 + 2 * c] : 0.f;   // floats 32..40
            b.e3[rr] = (c < 4) ? nbr[eb + 33 + 2 * c] : 0.f;   // floats 33..39
        }
        b.a1v = A1u[i * 64 + l];     // pair (2l, 2l+1) of A1b row
        b.av  = atom[i * 64 + l];
    } else {
        #pragma unroll
        for (int rr = 0; rr < 3; ++rr) {
            b.ga[rr] = b.gb[rr] = 0u;
            b.e0[rr] = b.e1[rr] = b.e2[rr] = b.e3[rr] = 0.f;
        }
        b.a1v = 0u; b.av = 0.f;
    }
    return b;
}

__global__ void k_msg(
    const float* __restrict__ atom, const float* __restrict__ nbr,
    const float* __restrict__ W, const int* __restrict__ idx,
    const unsigned* __restrict__ abf_u32, const unsigned short* __restrict__ A1b,
    float* __restrict__ X)
{
    __shared__ unsigned Au[4 * 16 * 68];  // per-wave 16 rows x 68 dw (128 bf16 + pad)
    const int tid = threadIdx.x;
    const int w = tid >> 6, l = tid & 63;
    const int c = l & 15, g = l >> 4;
    unsigned* Aw = &Au[w * 16 * 68];
    const unsigned* A1u = reinterpret_cast<const unsigned*>(A1b);

    // B fragments in registers (held across the whole kernel): 128 VGPRs
    short8 bf[8][4];
    #pragma unroll
    for (int nt = 0; nt < 8; ++nt)
      #pragma unroll
      for (int kk = 0; kk < 4; ++kk)
        #pragma unroll
        for (int j = 0; j < 8; ++j) {
            int col = nt * 16 + c;
            int k = g * 8 + kk * 32 + j;
            float wv = (k < 105) ? W[col * IN_DIM + 64 + k] : 0.f;  // nbr|edge blocks
            bf[nt][kk][j] = (short)f2bf(wv);
        }

    // zero pad rows 12..15 once (never rewritten)
    for (int t = l; t < 4 * 68; t += 64)
        Aw[12 * 68 + t] = 0u;

    const int TW = gridDim.x * 4;           // total waves
    const int gw = blockIdx.x * 4 + w;
    const int T = (N_ATOMS + TW - 1) / TW;

    // ---- pipeline warm-up ----
    int i0 = gw;
    bool act0 = (i0 < N_ATOMS);
    unsigned idxv0 = (l < 12 && act0) ? (unsigned)idx[i0 * M_NBRS + l] : 0u;
    Buf buf = issue_loads(i0, act0, idxv0, abf_u32, nbr, A1u, atom, c, g, l);
    int i1 = gw + TW;
    unsigned idxv_n = (l < 12 && i1 < N_ATOMS) ? (unsigned)idx[i1 * M_NBRS + l] : 0u;

    for (int t = 0; t < T; ++t) {
        int i = gw + t * TW;
        bool act = (i < N_ATOMS);
        int i_nxt = i + TW;
        bool act_n = (i_nxt < N_ATOMS);

        // ---- prefetch stage: issue loads for atom t+1, idx for t+2 ----
        Buf buf_n = issue_loads(i_nxt, act_n, idxv_n, abf_u32, nbr, A1u, atom, c, g, l);
        int i_n2 = i + 2 * TW;
        unsigned idxv_n2 = (l < 12 && i_n2 < N_ATOMS) ? (unsigned)idx[i_n2 * M_NBRS + l] : 0u;

        // ---- consume stage: atom i ----
        if (act) {
            #pragma unroll
            for (int rr = 0; rr < 3; ++rr) {
                int r = rr * 4 + g;
                Aw[r * 68 + c]      = buf.ga[rr];
                Aw[r * 68 + 16 + c] = buf.gb[rr];
                Aw[r * 68 + 32 + c] = pack_bf2(buf.e0[rr], buf.e1[rr]);
                Aw[r * 68 + 48 + c] = (c < 5) ? pack_bf2(buf.e2[rr], buf.e3[rr]) : 0u;
            }
            short8 af[4];
            #pragma unroll
            for (int kk = 0; kk < 4; ++kk) {
                union { uint4 u; short8 s; } u;
                u.u = *reinterpret_cast<const uint4*>(&Aw[c * 68 + kk * 16 + g * 4]);
                af[kk] = u.s;
            }
            #pragma unroll
            for (int p = 0; p < 4; ++p) {
                f32x4 accf = {0.f,0.f,0.f,0.f}, accc = {0.f,0.f,0.f,0.f};
                #pragma unroll
                for (int kk = 0; kk < 4; ++kk) {
                    accf = __builtin_amdgcn_mfma_f32_16x16x32_bf16(af[kk], bf[p][kk],     accf, 0,0,0);
                    accc = __builtin_amdgcn_mfma_f32_16x16x32_bf16(af[kk], bf[p + 4][kk], accc, 0,0,0);
                }
                // A1 row extraction via shfl (executed by all lanes)
                unsigned a1p = __shfl(buf.a1v, p * 8 + (c >> 1), 64);
                unsigned a1q = __shfl(buf.a1v, 32 + p * 8 + (c >> 1), 64);
                float a1f = bf2f((unsigned short)((c & 1) ? (a1p >> 16) : (a1p & 0xffffu)));
                float a1c = bf2f((unsigned short)((c & 1) ? (a1q >> 16) : (a1q & 0xffffu)));
                float ac  = __shfl(buf.av, p * 16 + c, 64);
                float gs = 0.f;
                if (g < 3) {   // rows 12..15 (pad) are exactly quad 3
                    #pragma unroll
                    for (int r4 = 0; r4 < 4; ++r4) {
                        float zf = accf[r4] + a1f;
                        float zc = accc[r4] + a1c;
                        gs += sigmoid_f(zf) * softplus_f(zc);
                    }
                }
                gs += __shfl_xor(gs, 16, 64);
                gs += __shfl_xor(gs, 32, 64);
                if (g == 0)
                    X[i * ATOM_F + p * 16 + c] = ac + gs;
            }
        }
        // ---- rotate pipeline registers ----
        buf = buf_n;
        idxv_n = idxv_n2;
    }
}

// ---------------------------------------------------------------------------
// BN stats, two stages, then in-place normalize + softplus.
// ---------------------------------------------------------------------------
#define S1_BLOCKS 256
__global__ void k_stats1(const float* __restrict__ X, float* __restrict__ PART)
{
    __shared__ float s1[256], s2[256];
    int tid = threadIdx.x;
    int f = tid & 63;
    int seg = blockIdx.x * 4 + (tid >> 6);   // S1_BLOCKS*4 segments
    float sum = 0.f, sq = 0.f;
    for (int a = seg; a < N_ATOMS; a += S1_BLOCKS * 4) {
        float x = X[a * ATOM_F + f];
        sum += x; sq += x * x;
    }
    s1[tid] = sum; s2[tid] = sq;
    __syncthreads();
    if (tid < 64) {
        PART[blockIdx.x * 128 + tid] = s1[tid] + s1[tid+64] + s1[tid+128] + s1[tid+192];
    } else if (tid < 128) {
        int ff = tid - 64;
        PART[blockIdx.x * 128 + tid] = s2[ff] + s2[ff+64] + s2[ff+128] + s2[ff+192];
    }
}

__global__ void k_stats2(const float* __restrict__ PART, const float* __restrict__ gamma,
                         const float* __restrict__ beta, float* __restrict__ MS)
{
    __shared__ float st[128];
    int t = threadIdx.x;
    float s = 0.f;
    #pragma unroll 8
    for (int b = 0; b < S1_BLOCKS; ++b) s += PART[b * 128 + t];
    st[t] = s;
    __syncthreads();
    if (t < 64) {
        float mean = st[t] * (1.f / N_ATOMS);
        float msq  = st[64 + t] * (1.f / N_ATOMS);
        float var  = msq - mean * mean;        // biased var, matches jnp.var
        float inv  = rsqrtf(var + 1e-5f);
        float sc   = inv * gamma[t];
        float sh   = beta[t] - mean * sc;
        MS[t] = sc;
        MS[64 + t] = sh;
    }
}

__global__ void k_final(float* __restrict__ X, const float* __restrict__ MS)
{
    int q = blockIdx.x * 256 + threadIdx.x;   // exactly N*64/4 threads
    const float4* MS4 = reinterpret_cast<const float4*>(MS);
    float4 x = reinterpret_cast<const float4*>(X)[q];
    float4 sc = MS4[q & 15];
    float4 sh = MS4[16 + (q & 15)];
    float4 o;
    o.x = softplus_f(x.x * sc.x + sh.x);
    o.y = softplus_f(x.y * sc.y + sh.y);
    o.z = softplus_f(x.z * sc.z + sh.z);
    o.w = softplus_f(x.w * sc.w + sh.w);
    reinterpret_cast<float4*>(X)[q] = o;
}

extern "C" void kernel_launch(void* const* d_in, const int* in_sizes, int n_in,
                              void* d_out, int out_size, void* d_ws, size_t ws_size,
                              hipStream_t stream)
{
    const float* atom  = (const float*)d_in[0];
    const float* nbr   = (const float*)d_in[1];
    const float* W     = (const float*)d_in[2];
    const float* bias  = (const float*)d_in[3];
    const float* gamma = (const float*)d_in[4];
    const float* beta  = (const float*)d_in[5];
    const int*   idx   = (const int*)d_in[6];
    float* X = (float*)d_out;   // x pre-BN lives in d_out, finalized in place

    char* ws = (char*)d_ws;
    unsigned* abf       = (unsigned*)ws;                               // N*64 bf16
    unsigned short* A1b = (unsigned short*)(ws + (size_t)N_ATOMS * 64 * 2);  // N*128 bf16
    float* PART         = (float*)(ws + (size_t)N_ATOMS * 64 * 2
                                      + (size_t)N_ATOMS * 128 * 2);    // S1_BLOCKS*128 f32
    float* MS           = PART + S1_BLOCKS * 128;                      // 128 f32

    hipLaunchKernelGGL(k_prep,   dim3(512),       dim3(256), 0, stream, atom, W, bias, abf, A1b);
    hipLaunchKernelGGL(k_msg,    dim3(2048),      dim3(256), 0, stream, atom, nbr, W, idx, abf, A1b, X);
    hipLaunchKernelGGL(k_stats1, dim3(S1_BLOCKS), dim3(256), 0, stream, X, PART);
    hipLaunchKernelGGL(k_stats2, dim3(1),         dim3(128), 0, stream, PART, gamma, beta, MS);
    hipLaunchKernelGGL(k_final,  dim3(6250),      dim3(256), 0, stream, X, MS);
}

// Round 3
// 492.468 us; speedup vs baseline: 1.8994x; 1.8994x over previous
//
#include <hip/hip_runtime.h>
#include <hip/hip_bf16.h>

#define N_ATOMS 100000
#define M_NBRS 12
#define ATOM_F 64
#define NBR_F 41
#define OUT_DIM 128   // 2*ATOM_F
#define IN_DIM 169    // 2*ATOM_F + NBR_F

typedef __attribute__((ext_vector_type(8))) short short8;
typedef __attribute__((ext_vector_type(4))) float f32x4;

__device__ __forceinline__ unsigned short f2bf(float f) {
    union { float f; unsigned u; } v; v.f = f;
    unsigned u = v.u;
    return (unsigned short)((u + 0x7fffu + ((u >> 16) & 1u)) >> 16);
}
__device__ __forceinline__ float bf2f(unsigned short h) {
    union { unsigned u; float f; } v; v.u = ((unsigned)h) << 16;
    return v.f;
}
__device__ __forceinline__ unsigned pack_bf2(float lo, float hi) {
    return (unsigned)f2bf(lo) | (((unsigned)f2bf(hi)) << 16);
}
__device__ __forceinline__ float softplus_f(float x) {
    return fmaxf(x, 0.f) + __logf(1.f + __expf(-fabsf(x)));
}
__device__ __forceinline__ float sigmoid_f(float x) {
    return 1.f / (1.f + __expf(-x));
}

// ---------------------------------------------------------------------------
// P: per-atom precompute. abf[i] = bf16(atom_fea[i]);  A1b[i][o] = bf16(
//    W_self[o]·a_i + b[o]).  MFMA 16x16x32, rows = 16 atoms, cols = 128.
// W_self staged via LDS (coalesced); A1b stores transposed via LDS for
// coalesced dwordx4 writes. Main loop barrier-free (wave-private LDS).
// ---------------------------------------------------------------------------
#define WS_STRIDE 72   // bf16 stride for Ws rows (144B, 16B-aligned)
__global__ __launch_bounds__(256, 4) void k_prep(
    const float* __restrict__ atom, const float* __restrict__ W,
    const float* __restrict__ bias, unsigned* __restrict__ abf_u32,
    unsigned* __restrict__ A1u_out)
{
    __shared__ unsigned short Ws[128 * WS_STRIDE];   // W_self bf16 [col][k]
    __shared__ unsigned Ap[4 * 16 * 36];             // per-wave A tile
    __shared__ unsigned short T1[4][16 * 136];       // per-wave A1 transpose
    const int tid = threadIdx.x;
    const int w = tid >> 6, l = tid & 63;
    const int r = l & 15, g = l >> 4;

    // stage W_self -> LDS bf16 (coalesced reads)
    for (int e = tid; e < 128 * 64; e += 256) {
        int col = e >> 6, k = e & 63;
        Ws[col * WS_STRIDE + k] = f2bf(W[col * IN_DIM + k]);
    }
    __syncthreads();

    // B fragments from LDS: lane holds B[k = g*8+kk*32+j][col = nt*16+r]
    short8 bf[8][2];
    #pragma unroll
    for (int nt = 0; nt < 8; ++nt)
      #pragma unroll
      for (int kk = 0; kk < 2; ++kk) {
            int col = nt * 16 + r;
            union { uint4 u; short8 s; } u;
            u.u = *reinterpret_cast<const uint4*>(&Ws[col * WS_STRIDE + kk * 32 + g * 8]);
            bf[nt][kk] = u.s;
      }

    float bb[8];
    #pragma unroll
    for (int nt = 0; nt < 8; ++nt) bb[nt] = bias[nt * 16 + r];

    const int totalw = gridDim.x * 4;
    const int gw = blockIdx.x * 4 + w;
    const int step = totalw * 16;
    const int T = (N_ATOMS + step - 1) / step;
    unsigned* Aw = &Ap[w * 16 * 36];
    unsigned short* Tw = T1[w];

    for (int t = 0; t < T; ++t) {
        int base = gw * 16 + t * step;
        // load 16 atoms x 64 f32 -> bf16 pack -> Aw
        #pragma unroll
        for (int sub = 0; sub < 4; ++sub) {
            int chunk = g * 4 + sub;          // 16 float4 chunks per row
            int a = base + r;
            float4 v = make_float4(0.f, 0.f, 0.f, 0.f);
            if (a < N_ATOMS)
                v = reinterpret_cast<const float4*>(atom)[a * 16 + chunk];
            Aw[r * 36 + chunk * 2]     = pack_bf2(v.x, v.y);
            Aw[r * 36 + chunk * 2 + 1] = pack_bf2(v.z, v.w);
        }
        // coalesced abf store: lane l -> atom l>>2, quarter l&3
        {
            int al = l >> 2, part = l & 3;
            int a = base + al;
            if (a < N_ATOMS) {
                uint4 d0 = *reinterpret_cast<const uint4*>(&Aw[al * 36 + part * 8]);
                uint4 d1 = *reinterpret_cast<const uint4*>(&Aw[al * 36 + part * 8 + 4]);
                reinterpret_cast<uint4*>(&abf_u32[a * 32 + part * 8])[0] = d0;
                reinterpret_cast<uint4*>(&abf_u32[a * 32 + part * 8 + 4])[0] = d1;
            }
        }
        short8 af[2];
        #pragma unroll
        for (int kk = 0; kk < 2; ++kk) {
            union { uint4 u; short8 s; } u;
            u.u = *reinterpret_cast<const uint4*>(&Aw[r * 36 + kk * 16 + g * 4]);
            af[kk] = u.s;
        }
        #pragma unroll
        for (int nt = 0; nt < 8; ++nt) {
            f32x4 acc = {0.f, 0.f, 0.f, 0.f};
            acc = __builtin_amdgcn_mfma_f32_16x16x32_bf16(af[0], bf[nt][0], acc, 0, 0, 0);
            acc = __builtin_amdgcn_mfma_f32_16x16x32_bf16(af[1], bf[nt][1], acc, 0, 0, 0);
            int col = nt * 16 + r;
            #pragma unroll
            for (int r4 = 0; r4 < 4; ++r4) {
                int al = g * 4 + r4;          // C row = quad*4 + reg
                Tw[al * 136 + col] = f2bf(acc[r4] + bb[nt]);
            }
        }
        // coalesced A1 store: lane l -> atom l>>2, quarter l&3 (16 dw each)
        {
            int al = l >> 2, part = l & 3;
            int a = base + al;
            if (a < N_ATOMS) {
                const unsigned* Twu = reinterpret_cast<const unsigned*>(&Tw[al * 136]);
                #pragma unroll
                for (int q = 0; q < 4; ++q) {
                    uint4 d = *reinterpret_cast<const uint4*>(&Twu[part * 16 + q * 4]);
                    reinterpret_cast<uint4*>(&A1u_out[a * 64 + part * 16 + q * 4])[0] = d;
                }
            }
        }
    }
}

// ---------------------------------------------------------------------------
// M: one wave per atom per iteration, software-pipelined (idx 2 ahead,
// gathers/edges/A1/atom 1 ahead). W_nbr|W_edge staged via LDS once per
// block, then held in 128 VGPRs. Barrier-free main loop (wave-private LDS).
// ---------------------------------------------------------------------------
struct Buf {
    unsigned ga[3], gb[3];            // gathered nbr bf16 (2 u32 per row)
    float e0[3], e1[3], e2[3], e3[3]; // raw edge floats
    unsigned a1v;                     // A1 row, 1 u32 (2 bf16) per lane
    float av;                         // atom row, 1 f32 per lane
};

__device__ __forceinline__ Buf issue_loads(
    int i, bool act, unsigned idxv,
    const unsigned* __restrict__ abf_u32, const float* __restrict__ nbr,
    const unsigned* __restrict__ A1u, const float* __restrict__ atom,
    int c, int g, int l)
{
    Buf b;
    if (act) {
        #pragma unroll
        for (int rr = 0; rr < 3; ++rr) {
            int r = rr * 4 + g;
            int j = (int)__shfl(idxv, r, 64);
            b.ga[rr] = abf_u32[j * 32 + c];
            b.gb[rr] = abf_u32[j * 32 + 16 + c];
            int eb = (i * M_NBRS + r) * NBR_F;
            b.e0[rr] = nbr[eb + 2 * c];
            b.e1[rr] = nbr[eb + 2 * c + 1];          // 2c+1 <= 31 < 41, safe
            b.e2[rr] = (c < 5) ? nbr[eb + 32 + 2 * c] : 0.f;   // floats 32..40
            b.e3[rr] = (c < 4) ? nbr[eb + 33 + 2 * c] : 0.f;   // floats 33..39
        }
        b.a1v = A1u[i * 64 + l];     // pair (2l, 2l+1) of A1 row
        b.av  = atom[i * 64 + l];
    } else {
        #pragma unroll
        for (int rr = 0; rr < 3; ++rr) {
            b.ga[rr] = b.gb[rr] = 0u;
            b.e0[rr] = b.e1[rr] = b.e2[rr] = b.e3[rr] = 0.f;
        }
        b.a1v = 0u; b.av = 0.f;
    }
    return b;
}

#define BS_STRIDE 136   // bf16 stride for Bs rows (272B, 16B-aligned)
__global__ __launch_bounds__(256, 2) void k_msg(
    const float* __restrict__ atom, const float* __restrict__ nbr,
    const float* __restrict__ W, const int* __restrict__ idx,
    const unsigned* __restrict__ abf_u32, const unsigned* __restrict__ A1u,
    float* __restrict__ X)
{
    __shared__ unsigned short Bs[128 * BS_STRIDE]; // [col][k] bf16, 34.8 KB
    __shared__ unsigned Au[4 * 16 * 68];           // per-wave A tile, 17.4 KB
    const int tid = threadIdx.x;
    const int w = tid >> 6, l = tid & 63;
    const int c = l & 15, g = l >> 4;
    unsigned* Aw = &Au[w * 16 * 68];

    // zero Bs (covers K-pad 105..127 and row pad)
    for (int e = tid; e < 128 * BS_STRIDE / 2; e += 256)
        reinterpret_cast<unsigned*>(Bs)[e] = 0u;
    __syncthreads();
    // stage W_nbr|W_edge -> LDS bf16 (coalesced reads)
    for (int e = tid; e < 128 * 105; e += 256) {
        unsigned col = (unsigned)e / 105u;
        unsigned k = (unsigned)e - col * 105u;
        Bs[col * BS_STRIDE + k] = f2bf(W[col * IN_DIM + 64 + k]);
    }
    __syncthreads();

    // B fragments from LDS into registers (held whole kernel): 128 VGPRs
    short8 bf[8][4];
    #pragma unroll
    for (int nt = 0; nt < 8; ++nt)
      #pragma unroll
      for (int kk = 0; kk < 4; ++kk) {
            int col = nt * 16 + c;
            union { uint4 u; short8 s; } u;
            u.u = *reinterpret_cast<const uint4*>(&Bs[col * BS_STRIDE + kk * 32 + g * 8]);
            bf[nt][kk] = u.s;
      }

    // zero pad rows 12..15 once (never rewritten)
    for (int t = l; t < 4 * 68; t += 64)
        Aw[12 * 68 + t] = 0u;

    const int TW = gridDim.x * 4;           // total waves
    const int gw = blockIdx.x * 4 + w;
    const int T = (N_ATOMS + TW - 1) / TW;

    // ---- pipeline warm-up ----
    int i0 = gw;
    bool act0 = (i0 < N_ATOMS);
    unsigned idxv0 = (l < 12 && act0) ? (unsigned)idx[i0 * M_NBRS + l] : 0u;
    Buf buf = issue_loads(i0, act0, idxv0, abf_u32, nbr, A1u, atom, c, g, l);
    int i1 = gw + TW;
    unsigned idxv_n = (l < 12 && i1 < N_ATOMS) ? (unsigned)idx[i1 * M_NBRS + l] : 0u;

    for (int t = 0; t < T; ++t) {
        int i = gw + t * TW;
        bool act = (i < N_ATOMS);
        int i_nxt = i + TW;
        bool act_n = (i_nxt < N_ATOMS);

        // ---- prefetch: loads for atom t+1, idx for t+2 ----
        Buf buf_n = issue_loads(i_nxt, act_n, idxv_n, abf_u32, nbr, A1u, atom, c, g, l);
        int i_n2 = i + 2 * TW;
        unsigned idxv_n2 = (l < 12 && i_n2 < N_ATOMS) ? (unsigned)idx[i_n2 * M_NBRS + l] : 0u;

        // ---- consume: atom i ----
        if (act) {
            #pragma unroll
            for (int rr = 0; rr < 3; ++rr) {
                int r = rr * 4 + g;
                Aw[r * 68 + c]      = buf.ga[rr];
                Aw[r * 68 + 16 + c] = buf.gb[rr];
                Aw[r * 68 + 32 + c] = pack_bf2(buf.e0[rr], buf.e1[rr]);
                Aw[r * 68 + 48 + c] = (c < 5) ? pack_bf2(buf.e2[rr], buf.e3[rr]) : 0u;
            }
            short8 af[4];
            #pragma unroll
            for (int kk = 0; kk < 4; ++kk) {
                union { uint4 u; short8 s; } u;
                u.u = *reinterpret_cast<const uint4*>(&Aw[c * 68 + kk * 16 + g * 4]);
                af[kk] = u.s;
            }
            #pragma unroll
            for (int p = 0; p < 4; ++p) {
                f32x4 accf = {0.f,0.f,0.f,0.f}, accc = {0.f,0.f,0.f,0.f};
                #pragma unroll
                for (int kk = 0; kk < 4; ++kk) {
                    accf = __builtin_amdgcn_mfma_f32_16x16x32_bf16(af[kk], bf[p][kk],     accf, 0,0,0);
                    accc = __builtin_amdgcn_mfma_f32_16x16x32_bf16(af[kk], bf[p + 4][kk], accc, 0,0,0);
                }
                // A1 row extraction via shfl (executed by all lanes)
                unsigned a1p = __shfl(buf.a1v, p * 8 + (c >> 1), 64);
                unsigned a1q = __shfl(buf.a1v, 32 + p * 8 + (c >> 1), 64);
                float a1f = bf2f((unsigned short)((c & 1) ? (a1p >> 16) : (a1p & 0xffffu)));
                float a1c = bf2f((unsigned short)((c & 1) ? (a1q >> 16) : (a1q & 0xffffu)));
                float ac  = __shfl(buf.av, p * 16 + c, 64);
                float gs = 0.f;
                if (g < 3) {   // rows 12..15 (pad) are exactly quad 3
                    #pragma unroll
                    for (int r4 = 0; r4 < 4; ++r4) {
                        float zf = accf[r4] + a1f;
                        float zc = accc[r4] + a1c;
                        gs += sigmoid_f(zf) * softplus_f(zc);
                    }
                }
                gs += __shfl_xor(gs, 16, 64);
                gs += __shfl_xor(gs, 32, 64);
                if (g == 0)
                    X[i * ATOM_F + p * 16 + c] = ac + gs;
            }
        }
        // ---- rotate pipeline registers ----
        buf = buf_n;
        idxv_n = idxv_n2;
    }
}

// ---------------------------------------------------------------------------
// BN stats, two stages, then in-place normalize + softplus.
// ---------------------------------------------------------------------------
#define S1_BLOCKS 256
__global__ void k_stats1(const float* __restrict__ X, float* __restrict__ PART)
{
    __shared__ float s1[256], s2[256];
    int tid = threadIdx.x;
    int f = tid & 63;
    int seg = blockIdx.x * 4 + (tid >> 6);   // S1_BLOCKS*4 segments
    float sum = 0.f, sq = 0.f;
    for (int a = seg; a < N_ATOMS; a += S1_BLOCKS * 4) {
        float x = X[a * ATOM_F + f];
        sum += x; sq += x * x;
    }
    s1[tid] = sum; s2[tid] = sq;
    __syncthreads();
    if (tid < 64) {
        PART[blockIdx.x * 128 + tid] = s1[tid] + s1[tid+64] + s1[tid+128] + s1[tid+192];
    } else if (tid < 128) {
        int ff = tid - 64;
        PART[blockIdx.x * 128 + tid] = s2[ff] + s2[ff+64] + s2[ff+128] + s2[ff+192];
    }
}

__global__ void k_stats2(const float* __restrict__ PART, const float* __restrict__ gamma,
                         const float* __restrict__ beta, float* __restrict__ MS)
{
    __shared__ float st[128];
    int t = threadIdx.x;
    float s = 0.f;
    #pragma unroll 8
    for (int b = 0; b < S1_BLOCKS; ++b) s += PART[b * 128 + t];
    st[t] = s;
    __syncthreads();
    if (t < 64) {
        float mean = st[t] * (1.f / N_ATOMS);
        float msq  = st[64 + t] * (1.f / N_ATOMS);
        float var  = msq - mean * mean;        // biased var, matches jnp.var
        float inv  = rsqrtf(var + 1e-5f);
        float sc   = inv * gamma[t];
        float sh   = beta[t] - mean * sc;
        MS[t] = sc;
        MS[64 + t] = sh;
    }
}

__global__ void k_final(float* __restrict__ X, const float* __restrict__ MS)
{
    int q = blockIdx.x * 256 + threadIdx.x;   // exactly N*64/4 threads
    const float4* MS4 = reinterpret_cast<const float4*>(MS);
    float4 x = reinterpret_cast<const float4*>(X)[q];
    float4 sc = MS4[q & 15];
    float4 sh = MS4[16 + (q & 15)];
    float4 o;
    o.x = softplus_f(x.x * sc.x + sh.x);
    o.y = softplus_f(x.y * sc.y + sh.y);
    o.z = softplus_f(x.z * sc.z + sh.z);
    o.w = softplus_f(x.w * sc.w + sh.w);
    reinterpret_cast<float4*>(X)[q] = o;
}

extern "C" void kernel_launch(void* const* d_in, const int* in_sizes, int n_in,
                              void* d_out, int out_size, void* d_ws, size_t ws_size,
                              hipStream_t stream)
{
    const float* atom  = (const float*)d_in[0];
    const float* nbr   = (const float*)d_in[1];
    const float* W     = (const float*)d_in[2];
    const float* bias  = (const float*)d_in[3];
    const float* gamma = (const float*)d_in[4];
    const float* beta  = (const float*)d_in[5];
    const int*   idx   = (const int*)d_in[6];
    float* X = (float*)d_out;   // x pre-BN lives in d_out, finalized in place

    char* ws = (char*)d_ws;
    unsigned* abf = (unsigned*)ws;                                     // N*64 bf16
    unsigned* A1u = (unsigned*)(ws + (size_t)N_ATOMS * 64 * 2);        // N*128 bf16
    float* PART   = (float*)(ws + (size_t)N_ATOMS * 64 * 2
                                + (size_t)N_ATOMS * 128 * 2);          // S1_BLOCKS*128 f32
    float* MS     = PART + S1_BLOCKS * 128;                            // 128 f32

    hipLaunchKernelGGL(k_prep,   dim3(512),       dim3(256), 0, stream, atom, W, bias, abf, A1u);
    hipLaunchKernelGGL(k_msg,    dim3(512),       dim3(256), 0, stream, atom, nbr, W, idx, abf, A1u, X);
    hipLaunchKernelGGL(k_stats1, dim3(S1_BLOCKS), dim3(256), 0, stream, X, PART);
    hipLaunchKernelGGL(k_stats2, dim3(1),         dim3(128), 0, stream, PART, gamma, beta, MS);
    hipLaunchKernelGGL(k_final,  dim3(6250),      dim3(256), 0, stream, X, MS);
}